// Round 1
// baseline (1036.285 us; speedup 1.0000x reference)
//
#include <hip/hip_runtime.h>
#include <hip/hip_bf16.h>
#include <hip/hip_fp16.h>
#include <stdint.h>

#define DIM 256
#define NG 8192
#define KDIM 512      // 2*DIM (concat [readout | h])
#define GDIM 1024     // 4*DIM gates
#define N_ITERS 6
#define GPB 32        // graphs per block
#define NBLK (NG / GPB)   // 256 blocks = 1 per CU
#define NTHR 512          // 8 waves

typedef __hip_bfloat16 bf16;
typedef __attribute__((ext_vector_type(8))) short bf16x8;
typedef __attribute__((ext_vector_type(4))) float f32x4;
typedef __attribute__((ext_vector_type(8))) unsigned short u16x8;

// ---------------- helpers --------------
__device__ __forceinline__ float fast_sigmoid(float v) {
    return 1.0f / (1.0f + __expf(-v));
}
__device__ __forceinline__ float fast_tanh(float v) {
    float e = __expf(2.0f * v);
    return (e - 1.0f) / (e + 1.0f);
}
__device__ __forceinline__ unsigned short f2bf(float v) {
    __hip_bfloat16 t = __float2bfloat16(v);
    unsigned short u; __builtin_memcpy(&u, &t, 2); return u;
}
__device__ __forceinline__ unsigned short f2h(float v) {
    __half t = __float2half_rn(v);
    unsigned short u; __builtin_memcpy(&u, &t, 2); return u;
}
__device__ __forceinline__ float h2f(unsigned short u) {
    __half t; __builtin_memcpy(&t, &u, 2);
    return __half2float(t);
}

// Block-local persistent state: A=[readout|h] bf16 (XOR-swizzled rows) + h fp32.
// 32KB + 32KB = 64KB static LDS.
struct SM {
    unsigned short Acat[GPB * KDIM];  // row-major [32][512] bf16 bits, byte ^= (row&7)<<4
    float h[GPB * DIM];               // [32][256] fp32
};

// ---------------- prep: CSR offsets + W fragment-major bf16 + fused bias ------------
// Gate-column reorder: n = 128*(d>>5) + 32*gate + (d&31)  (gate order i,f,g,o).
// => GEMM wave w (cols [128w,128w+128)) owns ALL 4 gates of d in [32w,32w+32):
//    acc frag nf = 2*gate + (dd>>4), col-in-frag = dd&15 -> cell math is lane-local.
// Wfrag layout: elem[((nfrag*16 + kstep)*64 + lane)*8 + j] = W[n=16*nfrag+(lane&15)][k=32*kstep+8*(lane>>4)+j]
// -> each MFMA B-fragment is one fully-coalesced 1KB wave load.
__global__ __launch_bounds__(256) void k_prep(const int* __restrict__ batch, int n_nodes,
        int* __restrict__ offs,
        const float* __restrict__ Wih, const float* __restrict__ Whh,
        const float* __restrict__ bih, const float* __restrict__ bhh,
        bf16* __restrict__ Wfrag, float* __restrict__ bsum) {
    const int idx = blockIdx.x * blockDim.x + threadIdx.x;
    if (idx < 64 * 16 * 64) {               // 65536 threads, one u16x8 each
        const int nfrag = idx >> 10;        // 0..63
        const int kstep = (idx >> 6) & 15;  // 0..15
        const int lane  = idx & 63;
        const int c  = nfrag * 16 + (lane & 15);        // gate-col n
        const int k0 = kstep * 32 + (lane >> 4) * 8;
        const int d  = ((c >> 7) << 5) | (c & 31);
        const int gt = (c >> 5) & 3;
        const int jsrc = gt * DIM + d;                  // source row in Wih/Whh
        u16x8 pk;
        #pragma unroll
        for (int j = 0; j < 8; ++j) {
            const int k = k0 + j;
            const float v = (k < DIM) ? Wih[(size_t)jsrc * DIM + k]
                                      : Whh[(size_t)jsrc * DIM + (k - DIM)];
            pk[j] = f2bf(v);
        }
        *(u16x8*)&Wfrag[(size_t)idx * 8] = pk;
    }
    if (idx < GDIM) {
        const int d  = ((idx >> 7) << 5) | (idx & 31);
        const int gt = (idx >> 5) & 3;
        const int jsrc = gt * DIM + d;
        bsum[idx] = bih[jsrc] + bhh[jsrc];
    }
    if (idx < n_nodes) {
        const int b  = batch[idx];
        const int bp = (idx == 0) ? -1 : batch[idx - 1];
        for (int g = bp + 1; g <= b; ++g) offs[g] = idx;
        if (idx == n_nodes - 1)
            for (int g = b + 1; g <= NG; ++g) offs[g] = n_nodes;
    }
}

// ---------------- attention phase (device fn, block-local) ----------------
// One wave per graph (4 graphs sequential per wave); 32-lane half per node row;
// online softmax in registers; explicit 1-deep prefetch with CLAMPED addresses so
// the load of row r+2 is in flight while row r is processed (no guard branch).
// FIRST: reads fp32 x and writes the fp16 copy. LAST: also writes fp32 readout to out.
template <bool FIRST, bool LAST>
__device__ __forceinline__ void att_phase(int w, int lane, int g0,
        const float* __restrict__ xf, unsigned short* __restrict__ xb,
        const int* __restrict__ offs, float* __restrict__ out,
        SM& sm, int nmax) {
    const int half = lane >> 5, hl = lane & 31;
    for (int gi = 0; gi < 4; ++gi) {
        const int gl = (w << 2) + gi;
        const int g  = g0 + gl;
        float hreg[8];
        {
            const float4 a = *(const float4*)&sm.h[gl * DIM + hl * 8];
            const float4 b = *(const float4*)&sm.h[gl * DIM + hl * 8 + 4];
            hreg[0] = a.x; hreg[1] = a.y; hreg[2] = a.z; hreg[3] = a.w;
            hreg[4] = b.x; hreg[5] = b.y; hreg[6] = b.z; hreg[7] = b.w;
        }
        const int start = offs[g], end = offs[g + 1];
        float m = 0.0f;          // running max; init 0 == max(seg_max, 0) clamp
        float s = 0.0f;
        float racc[8] = {0, 0, 0, 0, 0, 0, 0, 0};
        int r = start + half;

        float pf[8];             // FIRST prefetch regs
        u16x8 pk;                // !FIRST prefetch regs
        {
            const size_t ap = (size_t)min(r, nmax) * DIM + hl * 8;
            if constexpr (FIRST) {
                const float4 a = *(const float4*)&xf[ap];
                const float4 b = *(const float4*)&xf[ap + 4];
                pf[0] = a.x; pf[1] = a.y; pf[2] = a.z; pf[3] = a.w;
                pf[4] = b.x; pf[5] = b.y; pf[6] = b.z; pf[7] = b.w;
            } else {
                pk = *(const u16x8*)&xb[ap];
            }
        }
        for (; r < end; r += 2) {
            float xv[8];
            if constexpr (FIRST) {
                #pragma unroll
                for (int j = 0; j < 8; ++j) xv[j] = pf[j];
            } else {
                #pragma unroll
                for (int j = 0; j < 8; ++j) xv[j] = h2f(pk[j]);
            }
            // prefetch row r+2 (clamped; dummy past the end, discarded at loop exit)
            const size_t ap = (size_t)min(r + 2, nmax) * DIM + hl * 8;
            if constexpr (FIRST) {
                const float4 a = *(const float4*)&xf[ap];
                const float4 b = *(const float4*)&xf[ap + 4];
                pf[0] = a.x; pf[1] = a.y; pf[2] = a.z; pf[3] = a.w;
                pf[4] = b.x; pf[5] = b.y; pf[6] = b.z; pf[7] = b.w;
                u16x8 st;
                #pragma unroll
                for (int j = 0; j < 8; ++j) st[j] = f2h(xv[j]);
                *(u16x8*)&xb[(size_t)r * DIM + hl * 8] = st;   // own rows only: no cross-block race
            } else {
                pk = *(const u16x8*)&xb[ap];
            }
            float dt = 0.0f;
            #pragma unroll
            for (int j = 0; j < 8; ++j) dt = fmaf(xv[j], hreg[j], dt);
            #pragma unroll
            for (int off = 16; off > 0; off >>= 1) dt += __shfl_xor(dt, off);
            const float mn = fmaxf(m, dt);
            const float al = __expf(m - mn);
            const float e  = __expf(dt - mn);
            s = s * al + e;
            #pragma unroll
            for (int j = 0; j < 8; ++j) racc[j] = fmaf(racc[j], al, e * xv[j]);
            m = mn;
        }
        // merge the two halves (online-softmax merge)
        const float mo = __shfl_xor(m, 32);
        const float M  = fmaxf(m, mo);
        const float am = __expf(m - M);
        s *= am;
        #pragma unroll
        for (int j = 0; j < 8; ++j) racc[j] *= am;
        s += __shfl_xor(s, 32);
        #pragma unroll
        for (int j = 0; j < 8; ++j) racc[j] += __shfl_xor(racc[j], 32);
        const float inv = 1.0f / (s + 1e-8f);
        if (half == 0) {          // bf16 readout into swizzled A (k = 0..255)
            u16x8 ob;
            #pragma unroll
            for (int j = 0; j < 8; ++j) ob[j] = f2bf(racc[j] * inv);
            unsigned off = (unsigned)(gl * 1024 + hl * 16);
            off ^= (unsigned)((gl & 7) << 4);
            *(u16x8*)((char*)sm.Acat + off) = ob;
        } else if (LAST) {        // fp32 readout straight into out[:, 256:512]
            float o[8];
            #pragma unroll
            for (int j = 0; j < 8; ++j) o[j] = racc[j] * inv;
            *(float4*)&out[(size_t)g * KDIM + DIM + hl * 8]     = make_float4(o[0], o[1], o[2], o[3]);
            *(float4*)&out[(size_t)g * KDIM + DIM + hl * 8 + 4] = make_float4(o[4], o[5], o[6], o[7]);
        }
    }
}

// ---------------- fully fused kernel: 6x (att -> GEMM -> cell), block-local ----------------
// Block owns 32 graphs. A=[readout|h] bf16 in swizzled LDS; h fp32 in LDS; c in registers.
// GEMM: per wave 32x128 output tile, A from LDS (2-way-conflict-free b128 reads via XOR
// swizzle), B streamed from global Wfrag (coalesced 1KB fragment loads, L2-resident).
// No barriers inside the K-loop -> compiler pipelines B-loads under MFMA freely.
__global__ __launch_bounds__(NTHR) void k_fused(const float* __restrict__ xf,
        unsigned short* __restrict__ xb, const int* __restrict__ offs,
        const bf16* __restrict__ Wfrag, const float* __restrict__ bsum,
        float* __restrict__ out, int n_nodes) {
    __shared__ SM sm;
    const int tid  = threadIdx.x;
    const int w    = tid >> 6, lane = tid & 63;
    const int g0   = blockIdx.x * GPB;
    const int nmax = n_nodes - 1;

    for (int i = tid; i < GPB * KDIM; i += NTHR) sm.Acat[i] = 0;   // h-region must be bf16 zero
    for (int i = tid; i < GPB * DIM;  i += NTHR) sm.h[i] = 0.0f;

    float c_[2][2][4] = {};           // persistent cell state: 16 regs/lane
    float bv[8];
    #pragma unroll
    for (int nf = 0; nf < 8; ++nf) bv[nf] = bsum[w * 128 + nf * 16 + (lane & 15)];

    __syncthreads();

    const bf16* wb = Wfrag + (size_t)w * 65536 + (size_t)lane * 8;

    for (int it = 0; it < N_ITERS; ++it) {
        // ---- attention (reads sm.h, writes sm.Acat readout region) ----
        if (it == 0)                att_phase<true,  false>(w, lane, g0, xf, xb, offs, out, sm, nmax);
        else if (it < N_ITERS - 1)  att_phase<false, false>(w, lane, g0, xf, xb, offs, out, sm, nmax);
        else                        att_phase<false, true >(w, lane, g0, xf, xb, offs, out, sm, nmax);
        __syncthreads();

        // ---- GEMM: gates(32x1024) = A(32x512) @ W^T, wave w -> cols [128w, 128w+128) ----
        f32x4 acc[2][8] = {};
        #pragma unroll
        for (int kstep = 0; kstep < 16; ++kstep) {
            const int r0 = lane & 15;
            unsigned o0 = (unsigned)(r0 * 1024 + kstep * 64 + (lane >> 4) * 16)
                        ^ (unsigned)((r0 & 7) << 4);
            unsigned o1 = o0 + 16 * 1024;   // row+16 has same (row&7) -> same XOR
            const bf16x8 a0 = *(const bf16x8*)((const char*)sm.Acat + o0);
            const bf16x8 a1 = *(const bf16x8*)((const char*)sm.Acat + o1);
            #pragma unroll
            for (int nf = 0; nf < 8; ++nf) {
                const bf16x8 b = *(const bf16x8*)&wb[(size_t)nf * 8192 + kstep * 512];
                acc[0][nf] = __builtin_amdgcn_mfma_f32_16x16x32_bf16(a0, b, acc[0][nf], 0, 0, 0);
                acc[1][nf] = __builtin_amdgcn_mfma_f32_16x16x32_bf16(a1, b, acc[1][nf], 0, 0, 0);
            }
        }
        __syncthreads();   // all waves done reading sm.Acat/sm.h before cell overwrites

        // ---- LSTM cell: lane-local gates (nf = 2*gate + dhi), update c, write h ----
        #pragma unroll
        for (int mf = 0; mf < 2; ++mf) {
            #pragma unroll
            for (int dhi = 0; dhi < 2; ++dhi) {
                const int d = w * 32 + dhi * 16 + (lane & 15);
                #pragma unroll
                for (int rr = 0; rr < 4; ++rr) {
                    const int row = mf * 16 + (lane >> 4) * 4 + rr;
                    const float gi = acc[mf][0 + dhi][rr] + bv[0 + dhi];
                    const float gf = acc[mf][2 + dhi][rr] + bv[2 + dhi];
                    const float gg = acc[mf][4 + dhi][rr] + bv[4 + dhi];
                    const float go = acc[mf][6 + dhi][rr] + bv[6 + dhi];
                    const float cn = fast_sigmoid(gf) * c_[mf][dhi][rr]
                                   + fast_sigmoid(gi) * fast_tanh(gg);
                    const float hn = fast_sigmoid(go) * fast_tanh(cn);
                    c_[mf][dhi][rr] = cn;
                    sm.h[row * DIM + d] = hn;
                    unsigned ho = (unsigned)(row * 1024 + (DIM + d) * 2)
                                ^ (unsigned)((row & 7) << 4);
                    *(unsigned short*)((char*)sm.Acat + ho) = f2bf(hn);
                }
            }
        }
        __syncthreads();
    }

    // final h (fp32, from LDS) -> out[:, 0:256], coalesced float4
    for (int i = tid; i < GPB * 64; i += NTHR) {
        const int row = i >> 6;
        const int dq  = (i & 63) << 2;
        *(float4*)&out[(size_t)(g0 + row) * KDIM + dq] = *(const float4*)&sm.h[row * DIM + dq];
    }
}

extern "C" void kernel_launch(void* const* d_in, const int* in_sizes, int n_in,
                              void* d_out, int out_size, void* d_ws, size_t ws_size,
                              hipStream_t stream) {
    const float* x     = (const float*)d_in[0];
    const int*   batch = (const int*)d_in[1];
    // d_in[2] = n_graphs scalar (8192, hardcoded)
    const float* Wih   = (const float*)d_in[3];
    const float* Whh   = (const float*)d_in[4];
    const float* bih   = (const float*)d_in[5];
    const float* bhh   = (const float*)d_in[6];
    const int n_nodes  = in_sizes[0] / DIM;
    float* out = (float*)d_out;

    char* ws = (char*)d_ws;
    size_t off = 0;
    auto alloc = [&](size_t bytes) -> void* {
        off = (off + 255) & ~(size_t)255;
        void* p = ws + off;
        off += bytes;
        return p;
    };
    int*   offs  = (int*)  alloc((size_t)(NG + 1) * sizeof(int));
    bf16*  Wfrag = (bf16*) alloc((size_t)GDIM * KDIM * sizeof(bf16));
    float* bsum  = (float*)alloc((size_t)GDIM * sizeof(float));
    unsigned short* xb = (unsigned short*)alloc((size_t)n_nodes * DIM * sizeof(unsigned short));
    (void)ws_size; (void)n_in; (void)out_size;

    const int cover = (n_nodes > 64 * 16 * 64) ? n_nodes : 64 * 16 * 64;
    const int pb = (cover + 255) / 256;

    k_prep<<<pb, 256, 0, stream>>>(batch, n_nodes, offs, Wih, Whh, bih, bhh, Wfrag, bsum);
    k_fused<<<NBLK, NTHR, 0, stream>>>(x, xb, offs, Wfrag, bsum, out, n_nodes);
}

// Round 2
// 1031.043 us; speedup vs baseline: 1.0051x; 1.0051x over previous
//
#include <hip/hip_runtime.h>
#include <hip/hip_bf16.h>
#include <hip/hip_fp16.h>
#include <stdint.h>

#define DIM 256
#define NG 8192
#define KDIM 512      // 2*DIM (concat [readout | h])
#define GDIM 1024     // 4*DIM gates
#define N_ITERS 6
#define GPB 32        // graphs per block
#define NBLK (NG / GPB)   // 256 blocks = 1 per CU
#define NTHR 512          // 8 waves

typedef __hip_bfloat16 bf16;
typedef __attribute__((ext_vector_type(8))) short bf16x8;
typedef __attribute__((ext_vector_type(4))) float f32x4;
typedef __attribute__((ext_vector_type(8))) unsigned short u16x8;

// ---------------- helpers --------------
__device__ __forceinline__ float fast_sigmoid(float v) {
    return 1.0f / (1.0f + __expf(-v));
}
__device__ __forceinline__ float fast_tanh(float v) {
    float e = __expf(2.0f * v);
    return (e - 1.0f) / (e + 1.0f);
}
__device__ __forceinline__ unsigned short f2bf(float v) {
    __hip_bfloat16 t = __float2bfloat16(v);
    unsigned short u; __builtin_memcpy(&u, &t, 2); return u;
}
__device__ __forceinline__ unsigned short f2h(float v) {
    __half t = __float2half_rn(v);
    unsigned short u; __builtin_memcpy(&u, &t, 2); return u;
}
__device__ __forceinline__ float h2f(unsigned short u) {
    __half t; __builtin_memcpy(&t, &u, 2);
    return __half2float(t);
}

// Block-local persistent state: A=[readout|h] bf16 (XOR-swizzled rows) + h fp32.
// 32KB + 32KB = 64KB static LDS.
struct SM {
    unsigned short Acat[GPB * KDIM];  // row-major [32][512] bf16 bits, byte ^= (row&7)<<4
    float h[GPB * DIM];               // [32][256] fp32
};

// ---------------- prep: CSR offsets + W fragment-major bf16 + fused bias ------------
// Gate-column reorder: n = 128*(d>>5) + 32*gate + (d&31)  (gate order i,f,g,o).
// => GEMM wave w (cols [128w,128w+128)) owns ALL 4 gates of d in [32w,32w+32):
//    acc frag nf = 2*gate + (dd>>4), col-in-frag = dd&15 -> cell math is lane-local.
// Wfrag layout: elem[((nfrag*16 + kstep)*64 + lane)*8 + j] = W[n=16*nfrag+(lane&15)][k=32*kstep+8*(lane>>4)+j]
// -> each MFMA B-fragment is one fully-coalesced 1KB wave load.
__global__ __launch_bounds__(256) void k_prep(const int* __restrict__ batch, int n_nodes,
        int* __restrict__ offs,
        const float* __restrict__ Wih, const float* __restrict__ Whh,
        const float* __restrict__ bih, const float* __restrict__ bhh,
        bf16* __restrict__ Wfrag, float* __restrict__ bsum) {
    const int idx = blockIdx.x * blockDim.x + threadIdx.x;
    if (idx < 64 * 16 * 64) {               // 65536 threads, one u16x8 each
        const int nfrag = idx >> 10;        // 0..63
        const int kstep = (idx >> 6) & 15;  // 0..15
        const int lane  = idx & 63;
        const int c  = nfrag * 16 + (lane & 15);        // gate-col n
        const int k0 = kstep * 32 + (lane >> 4) * 8;
        const int d  = ((c >> 7) << 5) | (c & 31);
        const int gt = (c >> 5) & 3;
        const int jsrc = gt * DIM + d;                  // source row in Wih/Whh
        u16x8 pk;
        #pragma unroll
        for (int j = 0; j < 8; ++j) {
            const int k = k0 + j;
            const float v = (k < DIM) ? Wih[(size_t)jsrc * DIM + k]
                                      : Whh[(size_t)jsrc * DIM + (k - DIM)];
            pk[j] = f2bf(v);
        }
        *(u16x8*)&Wfrag[(size_t)idx * 8] = pk;
    }
    if (idx < GDIM) {
        const int d  = ((idx >> 7) << 5) | (idx & 31);
        const int gt = (idx >> 5) & 3;
        const int jsrc = gt * DIM + d;
        bsum[idx] = bih[jsrc] + bhh[jsrc];
    }
    if (idx < n_nodes) {
        const int b  = batch[idx];
        const int bp = (idx == 0) ? -1 : batch[idx - 1];
        for (int g = bp + 1; g <= b; ++g) offs[g] = idx;
        if (idx == n_nodes - 1)
            for (int g = b + 1; g <= NG; ++g) offs[g] = n_nodes;
    }
}

// ---------------- attention phase (device fn, block-local) ----------------
// One wave per graph (4 graphs sequential per wave); 32-lane half per node row;
// online softmax in registers; explicit 1-deep prefetch with CLAMPED addresses so
// the load of row r+2 is in flight while row r is processed (no guard branch).
// FIRST: reads fp32 x and writes the fp16 copy. LAST: also writes fp32 readout to out.
template <bool FIRST, bool LAST>
__device__ __forceinline__ void att_phase(int w, int lane, int g0,
        const float* __restrict__ xf, unsigned short* __restrict__ xb,
        const int* __restrict__ offs, float* __restrict__ out,
        SM& sm, int nmax) {
    const int half = lane >> 5, hl = lane & 31;
    for (int gi = 0; gi < 4; ++gi) {
        const int gl = (w << 2) + gi;
        const int g  = g0 + gl;
        float hreg[8];
        {
            const float4 a = *(const float4*)&sm.h[gl * DIM + hl * 8];
            const float4 b = *(const float4*)&sm.h[gl * DIM + hl * 8 + 4];
            hreg[0] = a.x; hreg[1] = a.y; hreg[2] = a.z; hreg[3] = a.w;
            hreg[4] = b.x; hreg[5] = b.y; hreg[6] = b.z; hreg[7] = b.w;
        }
        const int start = offs[g], end = offs[g + 1];
        float m = 0.0f;          // running max; init 0 == max(seg_max, 0) clamp
        float s = 0.0f;
        float racc[8] = {0, 0, 0, 0, 0, 0, 0, 0};
        int r = start + half;

        float pf[8];             // FIRST prefetch regs
        u16x8 pk;                // !FIRST prefetch regs
        {
            const size_t ap = (size_t)min(r, nmax) * DIM + hl * 8;
            if constexpr (FIRST) {
                const float4 a = *(const float4*)&xf[ap];
                const float4 b = *(const float4*)&xf[ap + 4];
                pf[0] = a.x; pf[1] = a.y; pf[2] = a.z; pf[3] = a.w;
                pf[4] = b.x; pf[5] = b.y; pf[6] = b.z; pf[7] = b.w;
            } else {
                pk = *(const u16x8*)&xb[ap];
            }
        }
        for (; r < end; r += 2) {
            float xv[8];
            if constexpr (FIRST) {
                #pragma unroll
                for (int j = 0; j < 8; ++j) xv[j] = pf[j];
            } else {
                #pragma unroll
                for (int j = 0; j < 8; ++j) xv[j] = h2f(pk[j]);
            }
            // prefetch row r+2 (clamped; dummy past the end, discarded at loop exit)
            const size_t ap = (size_t)min(r + 2, nmax) * DIM + hl * 8;
            if constexpr (FIRST) {
                const float4 a = *(const float4*)&xf[ap];
                const float4 b = *(const float4*)&xf[ap + 4];
                pf[0] = a.x; pf[1] = a.y; pf[2] = a.z; pf[3] = a.w;
                pf[4] = b.x; pf[5] = b.y; pf[6] = b.z; pf[7] = b.w;
                u16x8 st;
                #pragma unroll
                for (int j = 0; j < 8; ++j) st[j] = f2h(xv[j]);
                *(u16x8*)&xb[(size_t)r * DIM + hl * 8] = st;   // own rows only: no cross-block race
            } else {
                pk = *(const u16x8*)&xb[ap];
            }
            float dt = 0.0f;
            #pragma unroll
            for (int j = 0; j < 8; ++j) dt = fmaf(xv[j], hreg[j], dt);
            #pragma unroll
            for (int off = 16; off > 0; off >>= 1) dt += __shfl_xor(dt, off);
            const float mn = fmaxf(m, dt);
            const float al = __expf(m - mn);
            const float e  = __expf(dt - mn);
            s = s * al + e;
            #pragma unroll
            for (int j = 0; j < 8; ++j) racc[j] = fmaf(racc[j], al, e * xv[j]);
            m = mn;
        }
        // merge the two halves (online-softmax merge)
        const float mo = __shfl_xor(m, 32);
        const float M  = fmaxf(m, mo);
        const float am = __expf(m - M);
        s *= am;
        #pragma unroll
        for (int j = 0; j < 8; ++j) racc[j] *= am;
        s += __shfl_xor(s, 32);
        #pragma unroll
        for (int j = 0; j < 8; ++j) racc[j] += __shfl_xor(racc[j], 32);
        const float inv = 1.0f / (s + 1e-8f);
        if (half == 0) {          // bf16 readout into swizzled A (k = 0..255)
            u16x8 ob;
            #pragma unroll
            for (int j = 0; j < 8; ++j) ob[j] = f2bf(racc[j] * inv);
            unsigned off = (unsigned)(gl * 1024 + hl * 16);
            off ^= (unsigned)((gl & 7) << 4);
            *(u16x8*)((char*)sm.Acat + off) = ob;
        } else if (LAST) {        // fp32 readout straight into out[:, 256:512]
            float o[8];
            #pragma unroll
            for (int j = 0; j < 8; ++j) o[j] = racc[j] * inv;
            *(float4*)&out[(size_t)g * KDIM + DIM + hl * 8]     = make_float4(o[0], o[1], o[2], o[3]);
            *(float4*)&out[(size_t)g * KDIM + DIM + hl * 8 + 4] = make_float4(o[4], o[5], o[6], o[7]);
        }
    }
}

// ---------------- fully fused kernel: 6x (att -> GEMM -> cell), block-local ----------------
// Block owns 32 graphs. A=[readout|h] bf16 in swizzled LDS; h fp32 in LDS; c in registers.
// GEMM: per wave 32x128 output tile, A from LDS (2-way-conflict-free b128 reads via XOR
// swizzle), B streamed from global Wfrag (coalesced 1KB fragment loads, L2-resident).
// __launch_bounds__(512, 2): 2 waves/EU -> 256-VGPR budget. Round-1's (512) defaulted to a
// 128-VGPR cap and spilled the B-fragment pipeline to scratch inside the MFMA loop
// (~560 MB of symmetric scratch traffic in the counters). 8 waves = 1 block/CU is already
// pinned by 64 KB LDS, so the higher cap costs no occupancy.
__global__ __launch_bounds__(NTHR, 2) void k_fused(const float* __restrict__ xf,
        unsigned short* __restrict__ xb, const int* __restrict__ offs,
        const bf16* __restrict__ Wfrag, const float* __restrict__ bsum,
        float* __restrict__ out, int n_nodes) {
    __shared__ SM sm;
    const int tid  = threadIdx.x;
    const int w    = tid >> 6, lane = tid & 63;
    const int g0   = blockIdx.x * GPB;
    const int nmax = n_nodes - 1;

    for (int i = tid; i < GPB * KDIM; i += NTHR) sm.Acat[i] = 0;   // h-region must be bf16 zero
    for (int i = tid; i < GPB * DIM;  i += NTHR) sm.h[i] = 0.0f;

    float c_[2][2][4] = {};           // persistent cell state: 16 regs/lane
    float bv[8];
    #pragma unroll
    for (int nf = 0; nf < 8; ++nf) bv[nf] = bsum[w * 128 + nf * 16 + (lane & 15)];

    __syncthreads();

    const bf16* wb = Wfrag + (size_t)w * 65536 + (size_t)lane * 8;

    for (int it = 0; it < N_ITERS; ++it) {
        // ---- attention (reads sm.h, writes sm.Acat readout region) ----
        if (it == 0)                att_phase<true,  false>(w, lane, g0, xf, xb, offs, out, sm, nmax);
        else if (it < N_ITERS - 1)  att_phase<false, false>(w, lane, g0, xf, xb, offs, out, sm, nmax);
        else                        att_phase<false, true >(w, lane, g0, xf, xb, offs, out, sm, nmax);
        __syncthreads();

        // ---- GEMM: gates(32x1024) = A(32x512) @ W^T, wave w -> cols [128w, 128w+128) ----
        f32x4 acc[2][8] = {};
        #pragma unroll
        for (int kstep = 0; kstep < 16; ++kstep) {
            const int r0 = lane & 15;
            unsigned o0 = (unsigned)(r0 * 1024 + kstep * 64 + (lane >> 4) * 16)
                        ^ (unsigned)((r0 & 7) << 4);
            unsigned o1 = o0 + 16 * 1024;   // row+16 has same (row&7) -> same XOR
            const bf16x8 a0 = *(const bf16x8*)((const char*)sm.Acat + o0);
            const bf16x8 a1 = *(const bf16x8*)((const char*)sm.Acat + o1);
            #pragma unroll
            for (int nf = 0; nf < 8; ++nf) {
                const bf16x8 b = *(const bf16x8*)&wb[(size_t)nf * 8192 + kstep * 512];
                acc[0][nf] = __builtin_amdgcn_mfma_f32_16x16x32_bf16(a0, b, acc[0][nf], 0, 0, 0);
                acc[1][nf] = __builtin_amdgcn_mfma_f32_16x16x32_bf16(a1, b, acc[1][nf], 0, 0, 0);
            }
        }
        __syncthreads();   // all waves done reading sm.Acat/sm.h before cell overwrites

        // ---- LSTM cell: lane-local gates (nf = 2*gate + dhi), update c, write h ----
        #pragma unroll
        for (int mf = 0; mf < 2; ++mf) {
            #pragma unroll
            for (int dhi = 0; dhi < 2; ++dhi) {
                const int d = w * 32 + dhi * 16 + (lane & 15);
                #pragma unroll
                for (int rr = 0; rr < 4; ++rr) {
                    const int row = mf * 16 + (lane >> 4) * 4 + rr;
                    const float gi = acc[mf][0 + dhi][rr] + bv[0 + dhi];
                    const float gf = acc[mf][2 + dhi][rr] + bv[2 + dhi];
                    const float gg = acc[mf][4 + dhi][rr] + bv[4 + dhi];
                    const float go = acc[mf][6 + dhi][rr] + bv[6 + dhi];
                    const float cn = fast_sigmoid(gf) * c_[mf][dhi][rr]
                                   + fast_sigmoid(gi) * fast_tanh(gg);
                    const float hn = fast_sigmoid(go) * fast_tanh(cn);
                    c_[mf][dhi][rr] = cn;
                    sm.h[row * DIM + d] = hn;
                    unsigned ho = (unsigned)(row * 1024 + (DIM + d) * 2)
                                ^ (unsigned)((row & 7) << 4);
                    *(unsigned short*)((char*)sm.Acat + ho) = f2bf(hn);
                }
            }
        }
        __syncthreads();
    }

    // final h (fp32, from LDS) -> out[:, 0:256], coalesced float4
    for (int i = tid; i < GPB * 64; i += NTHR) {
        const int row = i >> 6;
        const int dq  = (i & 63) << 2;
        *(float4*)&out[(size_t)(g0 + row) * KDIM + dq] = *(const float4*)&sm.h[row * DIM + dq];
    }
}

extern "C" void kernel_launch(void* const* d_in, const int* in_sizes, int n_in,
                              void* d_out, int out_size, void* d_ws, size_t ws_size,
                              hipStream_t stream) {
    const float* x     = (const float*)d_in[0];
    const int*   batch = (const int*)d_in[1];
    // d_in[2] = n_graphs scalar (8192, hardcoded)
    const float* Wih   = (const float*)d_in[3];
    const float* Whh   = (const float*)d_in[4];
    const float* bih   = (const float*)d_in[5];
    const float* bhh   = (const float*)d_in[6];
    const int n_nodes  = in_sizes[0] / DIM;
    float* out = (float*)d_out;

    char* ws = (char*)d_ws;
    size_t off = 0;
    auto alloc = [&](size_t bytes) -> void* {
        off = (off + 255) & ~(size_t)255;
        void* p = ws + off;
        off += bytes;
        return p;
    };
    int*   offs  = (int*)  alloc((size_t)(NG + 1) * sizeof(int));
    bf16*  Wfrag = (bf16*) alloc((size_t)GDIM * KDIM * sizeof(bf16));
    float* bsum  = (float*)alloc((size_t)GDIM * sizeof(float));
    unsigned short* xb = (unsigned short*)alloc((size_t)n_nodes * DIM * sizeof(unsigned short));
    (void)ws_size; (void)n_in; (void)out_size;

    const int cover = (n_nodes > 64 * 16 * 64) ? n_nodes : 64 * 16 * 64;
    const int pb = (cover + 255) / 256;

    k_prep<<<pb, 256, 0, stream>>>(batch, n_nodes, offs, Wih, Whh, bih, bhh, Wfrag, bsum);
    k_fused<<<NBLK, NTHR, 0, stream>>>(x, xb, offs, Wfrag, bsum, out, n_nodes);
}

// Round 3
// 914.935 us; speedup vs baseline: 1.1326x; 1.1269x over previous
//
#include <hip/hip_runtime.h>
#include <hip/hip_bf16.h>
#include <hip/hip_fp16.h>
#include <stdint.h>

#define DIM 256
#define NG 8192
#define KDIM 512      // 2*DIM (concat [readout | h])
#define GDIM 1024     // 4*DIM gates
#define N_ITERS 6
#define GPB 32        // graphs per block
#define NBLK (NG / GPB)   // 256 blocks = 1 per CU
#define NTHR 512          // 8 waves

typedef __hip_bfloat16 bf16;
typedef __attribute__((ext_vector_type(8))) short bf16x8;
typedef __attribute__((ext_vector_type(4))) float f32x4;
typedef __attribute__((ext_vector_type(8))) unsigned short u16x8;

// ---------------- helpers --------------
__device__ __forceinline__ float fast_sigmoid(float v) {
    return 1.0f / (1.0f + __expf(-v));
}
__device__ __forceinline__ float fast_tanh(float v) {
    float e = __expf(2.0f * v);
    return (e - 1.0f) / (e + 1.0f);
}
__device__ __forceinline__ unsigned short f2bf(float v) {
    __hip_bfloat16 t = __float2bfloat16(v);
    unsigned short u; __builtin_memcpy(&u, &t, 2); return u;
}
__device__ __forceinline__ unsigned short f2h(float v) {
    __half t = __float2half_rn(v);
    unsigned short u; __builtin_memcpy(&u, &t, 2); return u;
}
__device__ __forceinline__ float h2f(unsigned short u) {
    __half t; __builtin_memcpy(&t, &u, 2);
    return __half2float(t);
}

// Block-local persistent state: A=[readout|h] bf16 (XOR-swizzled rows) + h fp32.
// 32KB + 32KB = 64KB static LDS.
struct SM {
    unsigned short Acat[GPB * KDIM];  // row-major [32][512] bf16 bits, byte ^= (row&7)<<4
    float h[GPB * DIM];               // [32][256] fp32
};

// ---------------- prep: CSR offsets + W fragment-major bf16 + fused bias ------------
// Gate-column reorder: n = 128*(d>>5) + 32*gate + (d&31)  (gate order i,f,g,o).
// Wfrag layout: elem[((nfrag*16 + kstep)*64 + lane)*8 + j] = W[n=16*nfrag+(lane&15)][k=32*kstep+8*(lane>>4)+j]
// -> each MFMA B-fragment is one fully-coalesced 1KB wave load.
__global__ __launch_bounds__(256) void k_prep(const int* __restrict__ batch, int n_nodes,
        int* __restrict__ offs,
        const float* __restrict__ Wih, const float* __restrict__ Whh,
        const float* __restrict__ bih, const float* __restrict__ bhh,
        bf16* __restrict__ Wfrag, float* __restrict__ bsum) {
    const int idx = blockIdx.x * blockDim.x + threadIdx.x;
    if (idx < 64 * 16 * 64) {               // 65536 threads, one u16x8 each
        const int nfrag = idx >> 10;        // 0..63
        const int kstep = (idx >> 6) & 15;  // 0..15
        const int lane  = idx & 63;
        const int c  = nfrag * 16 + (lane & 15);        // gate-col n
        const int k0 = kstep * 32 + (lane >> 4) * 8;
        const int d  = ((c >> 7) << 5) | (c & 31);
        const int gt = (c >> 5) & 3;
        const int jsrc = gt * DIM + d;                  // source row in Wih/Whh
        u16x8 pk;
        #pragma unroll
        for (int j = 0; j < 8; ++j) {
            const int k = k0 + j;
            const float v = (k < DIM) ? Wih[(size_t)jsrc * DIM + k]
                                      : Whh[(size_t)jsrc * DIM + (k - DIM)];
            pk[j] = f2bf(v);
        }
        *(u16x8*)&Wfrag[(size_t)idx * 8] = pk;
    }
    if (idx < GDIM) {
        const int d  = ((idx >> 7) << 5) | (idx & 31);
        const int gt = (idx >> 5) & 3;
        const int jsrc = gt * DIM + d;
        bsum[idx] = bih[jsrc] + bhh[jsrc];
    }
    if (idx < n_nodes) {
        const int b  = batch[idx];
        const int bp = (idx == 0) ? -1 : batch[idx - 1];
        for (int g = bp + 1; g <= b; ++g) offs[g] = idx;
        if (idx == n_nodes - 1)
            for (int g = b + 1; g <= NG; ++g) offs[g] = n_nodes;
    }
}

// ---------------- attention phase (device fn, block-local, BATCHED) ----------------
// One wave per graph (4 graphs sequential); each 32-lane half owns alternating rows.
// Rows processed in batches of 4 per half (8/wave-iter), software-pipelined one batch
// ahead: 4 (or 8 for FIRST) independent global loads in flight at all times. Invalid
// rows (past `end`) use clamped addresses and dt=-1e30 so e=exp()=0 contributes nothing.
// FIRST: reads fp32 x, writes the fp16 copy. LAST: also writes fp32 readout to out.
template <bool FIRST, bool LAST>
__device__ __forceinline__ void att_phase(int w, int lane, int g0,
        const float* __restrict__ xf, unsigned short* __restrict__ xb,
        const int* __restrict__ offs, float* __restrict__ out,
        SM& sm, int nmax) {
    const int half = lane >> 5, hl = lane & 31;
    #pragma unroll 1
    for (int gi = 0; gi < 4; ++gi) {
        const int gl = (w << 2) + gi;
        const int g  = g0 + gl;
        const int start = offs[g], end = offs[g + 1];
        const int nb = (end - start + 7) >> 3;   // batches of 8 rows (4 per half)

        // issue batch-0 loads immediately (clamped)
        float4 curA[4], curB[4];   // FIRST
        u16x8  curP[4];            // !FIRST
        #pragma unroll
        for (int j = 0; j < 4; ++j) {
            const int r = start + half + 2 * j;
            const size_t ap = (size_t)min(r, nmax) * DIM + hl * 8;
            if constexpr (FIRST) {
                curA[j] = *(const float4*)&xf[ap];
                curB[j] = *(const float4*)&xf[ap + 4];
            } else {
                curP[j] = *(const u16x8*)&xb[ap];
            }
        }

        float hreg[8];
        {
            const float4 a = *(const float4*)&sm.h[gl * DIM + hl * 8];
            const float4 b = *(const float4*)&sm.h[gl * DIM + hl * 8 + 4];
            hreg[0] = a.x; hreg[1] = a.y; hreg[2] = a.z; hreg[3] = a.w;
            hreg[4] = b.x; hreg[5] = b.y; hreg[6] = b.z; hreg[7] = b.w;
        }

        float m = 0.0f;          // running max; init 0 == max(seg_max, 0) clamp
        float s = 0.0f;
        float racc[8] = {0, 0, 0, 0, 0, 0, 0, 0};

        #pragma unroll 1
        for (int b = 0; b < nb; ++b) {
            // ---- issue batch b+1 loads (clamped; garbage past end is discarded) ----
            float4 nxtA[4], nxtB[4];
            u16x8  nxtP[4];
            #pragma unroll
            for (int j = 0; j < 4; ++j) {
                const int r = start + half + 2 * (4 * (b + 1) + j);
                const size_t ap = (size_t)min(r, nmax) * DIM + hl * 8;
                if constexpr (FIRST) {
                    nxtA[j] = *(const float4*)&xf[ap];
                    nxtB[j] = *(const float4*)&xf[ap + 4];
                } else {
                    nxtP[j] = *(const u16x8*)&xb[ap];
                }
            }
            // ---- unpack + 4 dots ----
            float xv[4][8];
            float dt[4];
            #pragma unroll
            for (int j = 0; j < 4; ++j) {
                if constexpr (FIRST) {
                    xv[j][0] = curA[j].x; xv[j][1] = curA[j].y;
                    xv[j][2] = curA[j].z; xv[j][3] = curA[j].w;
                    xv[j][4] = curB[j].x; xv[j][5] = curB[j].y;
                    xv[j][6] = curB[j].z; xv[j][7] = curB[j].w;
                } else {
                    #pragma unroll
                    for (int i = 0; i < 8; ++i) xv[j][i] = h2f(curP[j][i]);
                }
                float d = 0.0f;
                #pragma unroll
                for (int i = 0; i < 8; ++i) d = fmaf(xv[j][i], hreg[i], d);
                dt[j] = d;
            }
            // ---- 4 interleaved 32-lane reductions (4 independent chains) ----
            #pragma unroll
            for (int off = 16; off > 0; off >>= 1) {
                #pragma unroll
                for (int j = 0; j < 4; ++j) dt[j] += __shfl_xor(dt[j], off);
            }
            // ---- sequential online-softmax updates (cheap VALU) ----
            #pragma unroll
            for (int j = 0; j < 4; ++j) {
                const int r = start + half + 2 * (4 * b + j);
                const float d  = (r < end) ? dt[j] : -1e30f;
                const float mn = fmaxf(m, d);
                const float al = __expf(m - mn);
                const float e  = __expf(d - mn);
                s = s * al + e;
                #pragma unroll
                for (int i = 0; i < 8; ++i) racc[i] = fmaf(racc[i], al, e * xv[j][i]);
                m = mn;
                if constexpr (FIRST) {        // persist fp16 copy (own rows only)
                    if (r < end) {
                        u16x8 st;
                        #pragma unroll
                        for (int i = 0; i < 8; ++i) st[i] = f2h(xv[j][i]);
                        *(u16x8*)&xb[(size_t)r * DIM + hl * 8] = st;
                    }
                }
            }
            // ---- rotate pipeline ----
            #pragma unroll
            for (int j = 0; j < 4; ++j) {
                if constexpr (FIRST) { curA[j] = nxtA[j]; curB[j] = nxtB[j]; }
                else                 { curP[j] = nxtP[j]; }
            }
        }

        // merge the two halves (online-softmax merge)
        const float mo = __shfl_xor(m, 32);
        const float M  = fmaxf(m, mo);
        const float am = __expf(m - M);
        s *= am;
        #pragma unroll
        for (int j = 0; j < 8; ++j) racc[j] *= am;
        s += __shfl_xor(s, 32);
        #pragma unroll
        for (int j = 0; j < 8; ++j) racc[j] += __shfl_xor(racc[j], 32);
        const float inv = 1.0f / (s + 1e-8f);
        if (half == 0) {          // bf16 readout into swizzled A (k = 0..255)
            u16x8 ob;
            #pragma unroll
            for (int j = 0; j < 8; ++j) ob[j] = f2bf(racc[j] * inv);
            unsigned off = (unsigned)(gl * 1024 + hl * 16);
            off ^= (unsigned)((gl & 7) << 4);
            *(u16x8*)((char*)sm.Acat + off) = ob;
        } else if (LAST) {        // fp32 readout straight into out[:, 256:512]
            float o[8];
            #pragma unroll
            for (int j = 0; j < 8; ++j) o[j] = racc[j] * inv;
            *(float4*)&out[(size_t)g * KDIM + DIM + hl * 8]     = make_float4(o[0], o[1], o[2], o[3]);
            *(float4*)&out[(size_t)g * KDIM + DIM + hl * 8 + 4] = make_float4(o[4], o[5], o[6], o[7]);
        }
    }
}

// ---------------- fully fused kernel: 6x (att -> GEMM -> cell), block-local ----------------
// Block owns 32 graphs. A=[readout|h] bf16 in swizzled LDS; h fp32 in LDS; c in registers.
// GEMM: per wave 32x128 output tile, A from LDS, B streamed from global Wfrag with an
// explicit register double-buffer (bcur/bnxt, 8 independent 1KB loads in flight under
// the 16 MFMAs of the current kstep). __launch_bounds__(512,2) caps VGPR at 256 so the
// allocator can keep the pipeline live.
__global__ __launch_bounds__(NTHR, 2) void k_fused(const float* __restrict__ xf,
        unsigned short* __restrict__ xb, const int* __restrict__ offs,
        const bf16* __restrict__ Wfrag, const float* __restrict__ bsum,
        float* __restrict__ out, int n_nodes) {
    __shared__ SM sm;
    const int tid  = threadIdx.x;
    const int w    = tid >> 6, lane = tid & 63;
    const int g0   = blockIdx.x * GPB;
    const int nmax = n_nodes - 1;

    for (int i = tid; i < GPB * KDIM; i += NTHR) sm.Acat[i] = 0;   // h-region must be bf16 zero
    for (int i = tid; i < GPB * DIM;  i += NTHR) sm.h[i] = 0.0f;

    float c_[2][2][4] = {};           // persistent cell state: 16 regs/lane
    float bv[8];
    #pragma unroll
    for (int nf = 0; nf < 8; ++nf) bv[nf] = bsum[w * 128 + nf * 16 + (lane & 15)];

    __syncthreads();

    const bf16* wb = Wfrag + (size_t)w * 65536 + (size_t)lane * 8;

    for (int it = 0; it < N_ITERS; ++it) {
        // ---- attention (reads sm.h, writes sm.Acat readout region) ----
        if (it == 0)                att_phase<true,  false>(w, lane, g0, xf, xb, offs, out, sm, nmax);
        else if (it < N_ITERS - 1)  att_phase<false, false>(w, lane, g0, xf, xb, offs, out, sm, nmax);
        else                        att_phase<false, true >(w, lane, g0, xf, xb, offs, out, sm, nmax);
        __syncthreads();

        // ---- GEMM: gates(32x1024) = A(32x512) @ W^T, wave w -> cols [128w, 128w+128) ----
        f32x4 acc[2][8] = {};
        const int r0 = lane & 15;
        bf16x8 bcur[8], bnxt[8];
        #pragma unroll
        for (int nf = 0; nf < 8; ++nf)
            bcur[nf] = *(const bf16x8*)&wb[(size_t)nf * 8192];
        #pragma unroll
        for (int kstep = 0; kstep < 16; ++kstep) {
            // issue next kstep's 8 B-fragment loads (wraps to 0 at the end; harmless)
            #pragma unroll
            for (int nf = 0; nf < 8; ++nf)
                bnxt[nf] = *(const bf16x8*)&wb[(size_t)nf * 8192 + ((kstep + 1) & 15) * 512];
            const unsigned o0 = (unsigned)(r0 * 1024 + kstep * 64 + (lane >> 4) * 16)
                              ^ (unsigned)((r0 & 7) << 4);
            const unsigned o1 = o0 + 16 * 1024;   // row+16 has same (row&7) -> same XOR
            const bf16x8 a0 = *(const bf16x8*)((const char*)sm.Acat + o0);
            const bf16x8 a1 = *(const bf16x8*)((const char*)sm.Acat + o1);
            #pragma unroll
            for (int nf = 0; nf < 8; ++nf) {
                acc[0][nf] = __builtin_amdgcn_mfma_f32_16x16x32_bf16(a0, bcur[nf], acc[0][nf], 0, 0, 0);
                acc[1][nf] = __builtin_amdgcn_mfma_f32_16x16x32_bf16(a1, bcur[nf], acc[1][nf], 0, 0, 0);
            }
            #pragma unroll
            for (int nf = 0; nf < 8; ++nf) bcur[nf] = bnxt[nf];
        }
        __syncthreads();   // all waves done reading sm.Acat/sm.h before cell overwrites

        // ---- LSTM cell: lane-local gates (nf = 2*gate + dhi), update c, write h ----
        #pragma unroll
        for (int mf = 0; mf < 2; ++mf) {
            #pragma unroll
            for (int dhi = 0; dhi < 2; ++dhi) {
                const int d = w * 32 + dhi * 16 + (lane & 15);
                #pragma unroll
                for (int rr = 0; rr < 4; ++rr) {
                    const int row = mf * 16 + (lane >> 4) * 4 + rr;
                    const float gi = acc[mf][0 + dhi][rr] + bv[0 + dhi];
                    const float gf = acc[mf][2 + dhi][rr] + bv[2 + dhi];
                    const float gg = acc[mf][4 + dhi][rr] + bv[4 + dhi];
                    const float go = acc[mf][6 + dhi][rr] + bv[6 + dhi];
                    const float cn = fast_sigmoid(gf) * c_[mf][dhi][rr]
                                   + fast_sigmoid(gi) * fast_tanh(gg);
                    const float hn = fast_sigmoid(go) * fast_tanh(cn);
                    c_[mf][dhi][rr] = cn;
                    sm.h[row * DIM + d] = hn;
                    unsigned ho = (unsigned)(row * 1024 + (DIM + d) * 2)
                                ^ (unsigned)((row & 7) << 4);
                    *(unsigned short*)((char*)sm.Acat + ho) = f2bf(hn);
                }
            }
        }
        __syncthreads();
    }

    // final h (fp32, from LDS) -> out[:, 0:256], coalesced float4
    for (int i = tid; i < GPB * 64; i += NTHR) {
        const int row = i >> 6;
        const int dq  = (i & 63) << 2;
        *(float4*)&out[(size_t)(g0 + row) * KDIM + dq] = *(const float4*)&sm.h[row * DIM + dq];
    }
}

extern "C" void kernel_launch(void* const* d_in, const int* in_sizes, int n_in,
                              void* d_out, int out_size, void* d_ws, size_t ws_size,
                              hipStream_t stream) {
    const float* x     = (const float*)d_in[0];
    const int*   batch = (const int*)d_in[1];
    // d_in[2] = n_graphs scalar (8192, hardcoded)
    const float* Wih   = (const float*)d_in[3];
    const float* Whh   = (const float*)d_in[4];
    const float* bih   = (const float*)d_in[5];
    const float* bhh   = (const float*)d_in[6];
    const int n_nodes  = in_sizes[0] / DIM;
    float* out = (float*)d_out;

    char* ws = (char*)d_ws;
    size_t off = 0;
    auto alloc = [&](size_t bytes) -> void* {
        off = (off + 255) & ~(size_t)255;
        void* p = ws + off;
        off += bytes;
        return p;
    };
    int*   offs  = (int*)  alloc((size_t)(NG + 1) * sizeof(int));
    bf16*  Wfrag = (bf16*) alloc((size_t)GDIM * KDIM * sizeof(bf16));
    float* bsum  = (float*)alloc((size_t)GDIM * sizeof(float));
    unsigned short* xb = (unsigned short*)alloc((size_t)n_nodes * DIM * sizeof(unsigned short));
    (void)ws_size; (void)n_in; (void)out_size;

    const int cover = (n_nodes > 64 * 16 * 64) ? n_nodes : 64 * 16 * 64;
    const int pb = (cover + 255) / 256;

    k_prep<<<pb, 256, 0, stream>>>(batch, n_nodes, offs, Wih, Whh, bih, bhh, Wfrag, bsum);
    k_fused<<<NBLK, NTHR, 0, stream>>>(x, xb, offs, Wfrag, bsum, out, n_nodes);
}